// Round 1
// baseline (4005.955 us; speedup 1.0000x reference)
//
#include <hip/hip_runtime.h>
#include <math.h>

#define D_TOT 480
#define XS_STRIDE 484   // pad 480 -> 484 (stride%32==4) to avoid LDS bank conflicts

// ---------------------------------------------------------------------------
// K0: M_b = (Wq_b . Wd_b . Wk_b^T) * scale_b  where scale folds ALL norms:
//   (1/sqrt(m))^2 from q,k linears, 1/sqrt(m*m*d) path norm,
//   1/sqrt(3) path count, 1/sqrt(480) self.scale
//   => scale_b = 1 / (m*m*sqrt(1440*d))
// logit_n = sum_b sum_d x_d^T M_b x_d
// ---------------------------------------------------------------------------
__global__ __launch_bounds__(256) void precompute_M(
    const float* __restrict__ Wq0, const float* __restrict__ Wq1, const float* __restrict__ Wq2,
    const float* __restrict__ Wk0, const float* __restrict__ Wk1, const float* __restrict__ Wk2,
    const float* __restrict__ Wd0, const float* __restrict__ Wd1, const float* __restrict__ Wd2,
    float* __restrict__ ws) {
  __shared__ float T[128 * 128];
  int b = blockIdx.x;
  const float *Wq, *Wk, *Wd;
  float* M;
  int m, deg;
  if (b == 0)      { Wq = Wq0; Wk = Wk0; Wd = Wd0; M = ws;          m = 128; deg = 1; }
  else if (b == 1) { Wq = Wq1; Wk = Wk1; Wd = Wd1; M = ws + 16384;  m = 64;  deg = 3; }
  else             { Wq = Wq2; Wk = Wk2; Wd = Wd2; M = ws + 20480;  m = 32;  deg = 5; }
  float scale = 1.0f / ((float)m * (float)m * sqrtf(1440.0f * (float)deg));
  // T = Wq . Wd
  for (int idx = threadIdx.x; idx < m * m; idx += 256) {
    int i = idx / m, c = idx % m;
    float s = 0.f;
    for (int a = 0; a < m; ++a) s += Wq[i * m + a] * Wd[a * m + c];
    T[idx] = s;
  }
  __syncthreads();
  // M = T . Wk^T  (scaled)
  for (int idx = threadIdx.x; idx < m * m; idx += 256) {
    int i = idx / m, j = idx % m;
    float s = 0.f;
    for (int c = 0; c < m; ++c) s += T[i * m + c] * Wk[j * m + c];
    M[idx] = s * scale;
  }
}

// ---------------------------------------------------------------------------
// K1: w[n] = exp( sum_b sum_d x_d^T M_b x_d )
// 16 nodes per block (staged in LDS), 16 threads per node.
// ---------------------------------------------------------------------------
__global__ __launch_bounds__(256) void logits_kernel(
    const float* __restrict__ f, const float* __restrict__ ws,
    float* __restrict__ w_out, int N) {
  __shared__ float xs[16 * XS_STRIDE];
  const float* M0 = ws;
  const float* M1 = ws + 16384;
  const float* M2 = ws + 20480;
  int t = threadIdx.x;
  int n0 = blockIdx.x * 16;

  // vectorized cooperative load: 16 rows x 120 float4
  for (int idx = t; idx < 16 * 120; idx += 256) {
    int node = idx / 120, e4 = idx % 120;
    int n = n0 + node;
    float4 v = make_float4(0.f, 0.f, 0.f, 0.f);
    if (n < N) v = reinterpret_cast<const float4*>(f)[(size_t)n * 120 + e4];
    *reinterpret_cast<float4*>(&xs[node * XS_STRIDE + e4 * 4]) = v;
  }
  __syncthreads();

  int node = t >> 4, l = t & 15;
  int n = n0 + node;
  const float* xrow = &xs[node * XS_STRIDE];
  float partial = 0.f;

  // irrep 0: 128x0e  (cols 0..127)
  {
    float s[8] = {0, 0, 0, 0, 0, 0, 0, 0};
    const float4* Mv = reinterpret_cast<const float4*>(M0);
    for (int i = 0; i < 128; ++i) {
      float xv = xrow[i];
      float4 a = Mv[(i * 128 + l * 8) >> 2];
      float4 c = Mv[((i * 128 + l * 8) >> 2) + 1];
      s[0] += xv * a.x; s[1] += xv * a.y; s[2] += xv * a.z; s[3] += xv * a.w;
      s[4] += xv * c.x; s[5] += xv * c.y; s[6] += xv * c.z; s[7] += xv * c.w;
    }
    for (int k = 0; k < 8; ++k) partial += s[k] * xrow[l * 8 + k];
  }
  // irrep 1: 64x1o  (cols 128 + 3*i + dd)
  for (int dd = 0; dd < 3; ++dd) {
    float s[4] = {0, 0, 0, 0};
    const float4* Mv = reinterpret_cast<const float4*>(M1);
    for (int i = 0; i < 64; ++i) {
      float xv = xrow[128 + 3 * i + dd];
      float4 a = Mv[(i * 64 + l * 4) >> 2];
      s[0] += xv * a.x; s[1] += xv * a.y; s[2] += xv * a.z; s[3] += xv * a.w;
    }
    for (int k = 0; k < 4; ++k) partial += s[k] * xrow[128 + 3 * (l * 4 + k) + dd];
  }
  // irrep 2: 32x2e  (cols 320 + 5*i + dd)
  for (int dd = 0; dd < 5; ++dd) {
    float s0 = 0.f, s1 = 0.f;
    const float2* Mv = reinterpret_cast<const float2*>(M2);
    for (int i = 0; i < 32; ++i) {
      float xv = xrow[320 + 5 * i + dd];
      float2 a = Mv[(i * 32 + l * 2) >> 1];
      s0 += xv * a.x; s1 += xv * a.y;
    }
    partial += s0 * xrow[320 + 5 * (l * 2) + dd] + s1 * xrow[320 + 5 * (l * 2 + 1) + dd];
  }

  // reduce across the node's 16 lanes
  for (int off = 8; off > 0; off >>= 1) partial += __shfl_xor(partial, off, 16);
  if (l == 0 && n < N) w_out[n] = expf(partial);
}

// ---------------------------------------------------------------------------
// K2: v = per-irrep (x . Wv)/sqrt(m); num[g] += w*v; norm[g] += w
// 128 nodes per block in 8 stages of 16; v computed in-place in the LDS tile;
// segmented (sorted-batch) reduction with register accumulators, atomics only
// on graph-boundary flush.
// ---------------------------------------------------------------------------
__global__ __launch_bounds__(256) void value_accum_kernel(
    const float* __restrict__ f,
    const float* __restrict__ Wv0, const float* __restrict__ Wv1, const float* __restrict__ Wv2,
    const float* __restrict__ w_arr, const int* __restrict__ batch,
    float* __restrict__ outnum, float* __restrict__ norm, int N) {
  __shared__ float xs[16 * XS_STRIDE];
  __shared__ int   gcache[16];
  __shared__ float wcache[16];
  int t = threadIdx.x;
  int c0 = t;        // always < 480
  int c1 = t + 256;  // valid if < 480
  float racc0 = 0.f, racc1 = 0.f, accw = 0.f;
  int cur_g = -1;
  const float sm0 = 0.08838834764831845f;  // 1/sqrt(128)
  const float sm1 = 0.125f;                // 1/sqrt(64)
  const float sm2 = 0.17677669529663687f;  // 1/sqrt(32)
  int blockBase = blockIdx.x * 128;

  for (int st = 0; st < 8; ++st) {
    int n0s = blockBase + st * 16;
    if (n0s >= N) break;
    int cnt = min(16, N - n0s);

    for (int idx = t; idx < 16 * 120; idx += 256) {
      int node = idx / 120, e4 = idx % 120;
      float4 v = make_float4(0.f, 0.f, 0.f, 0.f);
      if (node < cnt) v = reinterpret_cast<const float4*>(f)[(size_t)(n0s + node) * 120 + e4];
      *reinterpret_cast<float4*>(&xs[node * XS_STRIDE + e4 * 4]) = v;
    }
    if (t < 16) {
      gcache[t] = (t < cnt) ? batch[n0s + t] : 0;
      wcache[t] = (t < cnt) ? w_arr[n0s + t] : 0.f;
    }
    __syncthreads();

    // phase 1: v into xs in place (disjoint col residues across dd; wave-lockstep
    // within each 16-lane node group makes read-before-write safe)
    int node = t >> 4, l = t & 15;
    if (node < cnt) {
      float* xrow = &xs[node * XS_STRIDE];
      {
        float v[8] = {0, 0, 0, 0, 0, 0, 0, 0};
        const float4* Wv = reinterpret_cast<const float4*>(Wv0);
        for (int i = 0; i < 128; ++i) {
          float xv = xrow[i];
          float4 a = Wv[(i * 128 + l * 8) >> 2];
          float4 c = Wv[((i * 128 + l * 8) >> 2) + 1];
          v[0] += xv * a.x; v[1] += xv * a.y; v[2] += xv * a.z; v[3] += xv * a.w;
          v[4] += xv * c.x; v[5] += xv * c.y; v[6] += xv * c.z; v[7] += xv * c.w;
        }
        for (int k = 0; k < 8; ++k) xrow[l * 8 + k] = v[k] * sm0;
      }
      for (int dd = 0; dd < 3; ++dd) {
        float v[4] = {0, 0, 0, 0};
        const float4* Wv = reinterpret_cast<const float4*>(Wv1);
        for (int i = 0; i < 64; ++i) {
          float xv = xrow[128 + 3 * i + dd];
          float4 a = Wv[(i * 64 + l * 4) >> 2];
          v[0] += xv * a.x; v[1] += xv * a.y; v[2] += xv * a.z; v[3] += xv * a.w;
        }
        for (int k = 0; k < 4; ++k) xrow[128 + 3 * (l * 4 + k) + dd] = v[k] * sm1;
      }
      for (int dd = 0; dd < 5; ++dd) {
        float v0 = 0.f, v1 = 0.f;
        const float2* Wv = reinterpret_cast<const float2*>(Wv2);
        for (int i = 0; i < 32; ++i) {
          float xv = xrow[320 + 5 * i + dd];
          float2 a = Wv[(i * 32 + l * 2) >> 1];
          v0 += xv * a.x; v1 += xv * a.y;
        }
        xrow[320 + 5 * (l * 2) + dd]     = v0 * sm2;
        xrow[320 + 5 * (l * 2 + 1) + dd] = v1 * sm2;
      }
    }
    __syncthreads();

    // phase 2: segmented weighted accumulation (uniform control flow)
    for (int idx = 0; idx < cnt; ++idx) {
      int g = gcache[idx];
      float wn = wcache[idx];
      if (g != cur_g) {
        if (cur_g >= 0) {
          atomicAdd(&outnum[(size_t)cur_g * 480 + c0], racc0);
          if (c1 < 480) atomicAdd(&outnum[(size_t)cur_g * 480 + c1], racc1);
          if (t == 0) atomicAdd(&norm[cur_g], accw);
          racc0 = 0.f; racc1 = 0.f; accw = 0.f;
        }
        cur_g = g;
      }
      racc0 += wn * xs[idx * XS_STRIDE + c0];
      if (c1 < 480) racc1 += wn * xs[idx * XS_STRIDE + c1];
      if (t == 0) accw += wn;
    }
    __syncthreads();
  }
  if (cur_g >= 0) {
    atomicAdd(&outnum[(size_t)cur_g * 480 + c0], racc0);
    if (c1 < 480) atomicAdd(&outnum[(size_t)cur_g * 480 + c1], racc1);
    if (t == 0) atomicAdd(&norm[cur_g], accw);
  }
}

// ---------------------------------------------------------------------------
// K3: out = num / max(norm, 1e-8)
// ---------------------------------------------------------------------------
__global__ __launch_bounds__(256) void finalize_kernel(
    float* __restrict__ out, const float* __restrict__ norm, int total) {
  int idx = blockIdx.x * blockDim.x + threadIdx.x;
  if (idx < total) {
    int g = idx / 480;
    out[idx] = out[idx] / fmaxf(norm[g], 1e-8f);
  }
}

extern "C" void kernel_launch(void* const* d_in, const int* in_sizes, int n_in,
                              void* d_out, int out_size, void* d_ws, size_t ws_size,
                              hipStream_t stream) {
  const float* f   = (const float*)d_in[0];
  const float* Wq0 = (const float*)d_in[1];
  const float* Wq1 = (const float*)d_in[2];
  const float* Wq2 = (const float*)d_in[3];
  const float* Wk0 = (const float*)d_in[4];
  const float* Wk1 = (const float*)d_in[5];
  const float* Wk2 = (const float*)d_in[6];
  const float* Wv0 = (const float*)d_in[7];
  const float* Wv1 = (const float*)d_in[8];
  const float* Wv2 = (const float*)d_in[9];
  // Wd0..Wd2 = d_in[10..12]
  const int* batch = (const int*)d_in[13];

  int N = in_sizes[0] / D_TOT;
  int G = out_size / D_TOT;

  float* ws    = (float*)d_ws;
  float* w_arr = ws + 21504;        // [N]
  float* norm  = ws + 21504 + N;    // [G]
  float* out   = (float*)d_out;

  hipMemsetAsync(d_out, 0, (size_t)out_size * sizeof(float), stream);
  hipMemsetAsync(norm, 0, (size_t)G * sizeof(float), stream);

  precompute_M<<<3, 256, 0, stream>>>(
      (const float*)d_in[1], (const float*)d_in[2], (const float*)d_in[3],
      (const float*)d_in[4], (const float*)d_in[5], (const float*)d_in[6],
      (const float*)d_in[10], (const float*)d_in[11], (const float*)d_in[12], ws);

  logits_kernel<<<(N + 15) / 16, 256, 0, stream>>>(f, ws, w_arr, N);

  value_accum_kernel<<<(N + 127) / 128, 256, 0, stream>>>(
      f, Wv0, Wv1, Wv2, w_arr, batch, out, norm, N);

  finalize_kernel<<<(G * D_TOT + 255) / 256, 256, 0, stream>>>(out, norm, G * D_TOT);
}

// Round 2
// 2026.980 us; speedup vs baseline: 1.9763x; 1.9763x over previous
//
#include <hip/hip_runtime.h>
#include <math.h>

#define D_TOT 480
#define TB 640
#define TILE 16
#define XR_STRIDE 356   // 352 permuted irrep1/2 floats + 4 pad; row = 1424B (16B aligned)

// ---------------------------------------------------------------------------
// K0: M_b = (Wq_b . Wd_b . Wk_b^T) * scale_b, scale folds all e3nn norms:
//   scale_b = 1 / (m^2 * sqrt(1440*d)).  Strip-parallel: 16 rows per block.
// ws layout: M0 [16384], M1 [4096], M2 [1024]  (floats)
// ---------------------------------------------------------------------------
__global__ __launch_bounds__(256) void precompute_M(
    const float* __restrict__ Wq0, const float* __restrict__ Wq1, const float* __restrict__ Wq2,
    const float* __restrict__ Wk0, const float* __restrict__ Wk1, const float* __restrict__ Wk2,
    const float* __restrict__ Wd0, const float* __restrict__ Wd1, const float* __restrict__ Wd2,
    float* __restrict__ ws) {
  __shared__ float T[16 * 128];
  int b = blockIdx.x;
  const float *Wq, *Wk, *Wd;
  float* M;
  int m, deg, strip;
  if (b < 8)       { Wq = Wq0; Wk = Wk0; Wd = Wd0; M = ws;         m = 128; deg = 1; strip = b; }
  else if (b < 12) { Wq = Wq1; Wk = Wk1; Wd = Wd1; M = ws + 16384; m = 64;  deg = 3; strip = b - 8; }
  else if (b < 14) { Wq = Wq2; Wk = Wk2; Wd = Wd2; M = ws + 20480; m = 32;  deg = 5; strip = b - 12; }
  else return;
  int r0 = strip * 16;
  if (r0 >= m) return;
  float scale = 1.0f / ((float)m * (float)m * sqrtf(1440.0f * (float)deg));
  for (int idx = threadIdx.x; idx < 16 * m; idx += 256) {
    int r = idx / m, c = idx % m;
    float s = 0.f;
    for (int a = 0; a < m; ++a) s += Wq[(r0 + r) * m + a] * Wd[a * m + c];
    T[r * m + c] = s;
  }
  __syncthreads();
  for (int idx = threadIdx.x; idx < 16 * m; idx += 256) {
    int r = idx / m, j = idx % m;
    float s = 0.f;
    for (int c = 0; c < m; ++c) s += T[r * m + c] * Wk[j * m + c];
    M[(r0 + r) * m + j] = s * scale;
  }
}

// ---------------------------------------------------------------------------
// Fused: logits + exp + v + segmented pooling in ONE pass over f.
// Thread roles (block = 640 = 10 waves, each wave irrep-uniform):
//   t in [0,256):   irrep0, col c=t>>1, K-half (t&1)*64, 64 iters
//   t in [256,448): irrep1, dd=(t-256)>>6, j=(t-256)&63, 64 iters
//   t in [448,608): irrep2, dd=(t-448)>>5, j=(t-448)&31, 32 iters
//   t in [608,640): staging/reduction helper only
// x for irrep0 read straight from global (b128 broadcasts, L1-resident tile);
// irrep1/2 x pre-permuted into LDS ([dd][i'] contiguous) for b128 broadcasts.
// ---------------------------------------------------------------------------
__global__ __launch_bounds__(TB, 4) void fused_attn_kernel(
    const float* __restrict__ f, const float* __restrict__ M_all,
    const float* __restrict__ Wv0, const float* __restrict__ Wv1, const float* __restrict__ Wv2,
    const int* __restrict__ batch,
    float* __restrict__ outnum, float* __restrict__ norm,
    int N, int npb) {
  __shared__ __align__(16) float xs[TILE][XR_STRIDE];
  __shared__ float lds_logit[2][TILE];
  __shared__ int   lds_gi[2][TILE];

  int t = threadIdx.x;
  int n0 = blockIdx.x * npb;
  int nend = min(N, n0 + npb);
  if (n0 >= N) return;

  // role constants
  int role, corig = 0;
  float smv = 0.f;
  int c0 = 0, dd = 0, jj = 0, ib = 0;
  if (t < 256)      { role = 0; c0 = t >> 1; ib = (t & 1) << 6; corig = c0; smv = 0.08838834764831845f; }
  else if (t < 448) { role = 1; int u = t - 256; dd = u >> 6; jj = u & 63; corig = 128 + 3 * jj + dd; smv = 0.125f; }
  else if (t < 608) { role = 2; int u = t - 448; dd = u >> 5; jj = u & 31; corig = 320 + 5 * jj + dd; smv = 0.17677669529663687f; }
  else              { role = -1; }

  float racc = 0.f, naccw = 0.f;
  int cur_g = -1;
  int parity = 0;

  for (int nt = n0; nt < nend; nt += TILE, parity ^= 1) {
    const float* ftile = f + (size_t)nt * 480;

    // ---- stage permuted irrep1/2 x into LDS + graph ids + zero logits ----
    for (int idx = t; idx < TILE * 352; idx += TB) {
      int n = idx / 352, pp = idx - n * 352;
      int cs;
      if (pp < 192) cs = 128 + 3 * (pp & 63) + (pp >> 6);
      else { int q = pp - 192; cs = 320 + 5 * (q & 31) + (q >> 5); }
      xs[n][pp] = ftile[n * 480 + cs];
    }
    if (t < TILE) {
      lds_gi[parity][t] = batch[nt + t];
      lds_logit[parity][t] = 0.f;
    }
    __syncthreads();

    // ---- GEMM phase: u (logits) and v, 16 nodes, accum in regs ----
    float uacc[TILE], vacc[TILE], part[TILE];
#pragma unroll
    for (int n = 0; n < TILE; ++n) { uacc[n] = 0.f; vacc[n] = 0.f; part[n] = 0.f; }

    if (role == 0) {
      const float* fb = ftile + ib;
      for (int io = 0; io < 64; io += 4) {
        const float* Mp = M_all + (size_t)(ib + io) * 128 + c0;
        float m0 = Mp[0], m1 = Mp[128], m2 = Mp[256], m3 = Mp[384];
        const float* Wp = Wv0 + (size_t)(ib + io) * 128 + c0;
        float w0 = Wp[0], w1 = Wp[128], w2 = Wp[256], w3 = Wp[384];
#pragma unroll
        for (int n = 0; n < TILE; ++n) {
          float4 xv = *reinterpret_cast<const float4*>(fb + n * 480 + io);
          uacc[n] = fmaf(xv.x, m0, fmaf(xv.y, m1, fmaf(xv.z, m2, fmaf(xv.w, m3, uacc[n]))));
          vacc[n] = fmaf(xv.x, w0, fmaf(xv.y, w1, fmaf(xv.z, w2, fmaf(xv.w, w3, vacc[n]))));
        }
      }
      const float* fc = ftile + c0;
#pragma unroll
      for (int n = 0; n < TILE; ++n) part[n] = uacc[n] * fc[n * 480];
    } else if (role == 1) {
      const float* M1 = M_all + 16384;
      int xoff = dd * 64;
      for (int io = 0; io < 64; io += 4) {
        const float* Mp = M1 + (size_t)io * 64 + jj;
        float m0 = Mp[0], m1 = Mp[64], m2 = Mp[128], m3 = Mp[192];
        const float* Wp = Wv1 + (size_t)io * 64 + jj;
        float w0 = Wp[0], w1 = Wp[64], w2 = Wp[128], w3 = Wp[192];
#pragma unroll
        for (int n = 0; n < TILE; ++n) {
          float4 xv = *reinterpret_cast<const float4*>(&xs[n][xoff + io]);
          uacc[n] = fmaf(xv.x, m0, fmaf(xv.y, m1, fmaf(xv.z, m2, fmaf(xv.w, m3, uacc[n]))));
          vacc[n] = fmaf(xv.x, w0, fmaf(xv.y, w1, fmaf(xv.z, w2, fmaf(xv.w, w3, vacc[n]))));
        }
      }
#pragma unroll
      for (int n = 0; n < TILE; ++n) part[n] = uacc[n] * xs[n][xoff + jj];
    } else if (role == 2) {
      const float* M2 = M_all + 20480;
      int xoff = 192 + dd * 32;
      for (int io = 0; io < 32; io += 4) {
        const float* Mp = M2 + (size_t)io * 32 + jj;
        float m0 = Mp[0], m1 = Mp[32], m2 = Mp[64], m3 = Mp[96];
        const float* Wp = Wv2 + (size_t)io * 32 + jj;
        float w0 = Wp[0], w1 = Wp[32], w2 = Wp[64], w3 = Wp[96];
#pragma unroll
        for (int n = 0; n < TILE; ++n) {
          float4 xv = *reinterpret_cast<const float4*>(&xs[n][xoff + io]);
          uacc[n] = fmaf(xv.x, m0, fmaf(xv.y, m1, fmaf(xv.z, m2, fmaf(xv.w, m3, uacc[n]))));
          vacc[n] = fmaf(xv.x, w0, fmaf(xv.y, w1, fmaf(xv.z, w2, fmaf(xv.w, w3, vacc[n]))));
        }
      }
#pragma unroll
      for (int n = 0; n < TILE; ++n) part[n] = uacc[n] * xs[n][xoff + jj];
    }

    // ---- wave butterfly reduce partials, one LDS atomic per wave per n ----
#pragma unroll
    for (int n = 0; n < TILE; ++n) {
      float v = part[n];
      v += __shfl_xor(v, 1);  v += __shfl_xor(v, 2);  v += __shfl_xor(v, 4);
      v += __shfl_xor(v, 8);  v += __shfl_xor(v, 16); v += __shfl_xor(v, 32);
      part[n] = v;
    }
    if ((t & 63) == 0) {
#pragma unroll
      for (int n = 0; n < TILE; ++n) atomicAdd(&lds_logit[parity][n], part[n]);
    }
    __syncthreads();

    // ---- epilogue: w = exp(logit); segmented accumulation over sorted batch ----
    float wv[TILE];
#pragma unroll
    for (int n = 0; n < TILE; ++n) wv[n] = __expf(lds_logit[parity][n]);
#pragma unroll
    for (int n = 0; n < TILE; ++n) {
      int g = lds_gi[parity][n];
      if (g != cur_g) {
        if (cur_g >= 0) {
          if (role >= 0) atomicAdd(&outnum[(size_t)cur_g * 480 + corig], racc * smv);
          if (t == 0) atomicAdd(&norm[cur_g], naccw);
          racc = 0.f; naccw = 0.f;
        }
        cur_g = g;
      }
      racc += wv[n] * vacc[n];
      naccw += wv[n];
    }
    // next iteration's staging writes xs and the OTHER parity buffers only
  }
  if (cur_g >= 0) {
    if (role >= 0) atomicAdd(&outnum[(size_t)cur_g * 480 + corig], racc * smv);
    if (t == 0) atomicAdd(&norm[cur_g], naccw);
  }
}

// ---------------------------------------------------------------------------
// finalize: out = num / max(norm, 1e-8)
// ---------------------------------------------------------------------------
__global__ __launch_bounds__(256) void finalize_kernel(
    float* __restrict__ out, const float* __restrict__ norm, int total) {
  int idx = blockIdx.x * blockDim.x + threadIdx.x;
  if (idx < total) {
    int g = idx / 480;
    out[idx] = out[idx] / fmaxf(norm[g], 1e-8f);
  }
}

extern "C" void kernel_launch(void* const* d_in, const int* in_sizes, int n_in,
                              void* d_out, int out_size, void* d_ws, size_t ws_size,
                              hipStream_t stream) {
  const float* f   = (const float*)d_in[0];
  const float* Wv0 = (const float*)d_in[7];
  const float* Wv1 = (const float*)d_in[8];
  const float* Wv2 = (const float*)d_in[9];
  const int* batch = (const int*)d_in[13];

  int N = in_sizes[0] / D_TOT;
  int G = out_size / D_TOT;

  float* ws   = (float*)d_ws;       // M0/M1/M2: 21504 floats
  float* norm = ws + 21504;         // [G]
  float* out  = (float*)d_out;

  hipMemsetAsync(d_out, 0, (size_t)out_size * sizeof(float), stream);
  hipMemsetAsync(norm, 0, (size_t)G * sizeof(float), stream);

  precompute_M<<<14, 256, 0, stream>>>(
      (const float*)d_in[1], (const float*)d_in[2], (const float*)d_in[3],
      (const float*)d_in[4], (const float*)d_in[5], (const float*)d_in[6],
      (const float*)d_in[10], (const float*)d_in[11], (const float*)d_in[12], ws);

  int npb = ((N + 2047) / 2048 + 15) & ~15;
  if (npb < 16) npb = 16;
  int nblocks = (N + npb - 1) / npb;

  fused_attn_kernel<<<nblocks, TB, 0, stream>>>(
      f, ws, Wv0, Wv1, Wv2, batch, out, norm, N, npb);

  finalize_kernel<<<(G * D_TOT + 255) / 256, 256, 0, stream>>>(out, norm, G * D_TOT);
}

// Round 3
// 820.815 us; speedup vs baseline: 4.8805x; 2.4695x over previous
//
#include <hip/hip_runtime.h>
#include <math.h>

#define D_TOT 480

typedef short bf16x8 __attribute__((ext_vector_type(8)));
typedef float f32x4 __attribute__((ext_vector_type(4)));

#define MFMA16(a, b, c) __builtin_amdgcn_mfma_f32_16x16x32_bf16((a), (b), (c), 0, 0, 0)

static __device__ __forceinline__ unsigned short f2bf(float x) {
  unsigned u = __float_as_uint(x);
  u += 0x7FFFu + ((u >> 16) & 1u);   // RNE (inputs finite)
  return (unsigned short)(u >> 16);
}
static __device__ __forceinline__ float bf2f(unsigned short v) {
  return __uint_as_float(((unsigned)v) << 16);
}

// ---------------------------------------------------------------------------
// K0: Mtmp_b = (Wq_b . Wd_b . Wk_b^T) * scale_b (fp32), scale folds all norms:
//   scale_b = 1 / (m^2 * sqrt(1440*d)).
// ws fp32 layout: M0 [0,16384), M1 [16384,20480), M2 [20480,21504)
// ---------------------------------------------------------------------------
__global__ __launch_bounds__(256) void precompute_M(
    const float* __restrict__ Wq0, const float* __restrict__ Wq1, const float* __restrict__ Wq2,
    const float* __restrict__ Wk0, const float* __restrict__ Wk1, const float* __restrict__ Wk2,
    const float* __restrict__ Wd0, const float* __restrict__ Wd1, const float* __restrict__ Wd2,
    float* __restrict__ ws) {
  __shared__ float T[16 * 128];
  int b = blockIdx.x;
  const float *Wq, *Wk, *Wd;
  float* M;
  int m, deg, strip;
  if (b < 8)       { Wq = Wq0; Wk = Wk0; Wd = Wd0; M = ws;         m = 128; deg = 1; strip = b; }
  else if (b < 12) { Wq = Wq1; Wk = Wk1; Wd = Wd1; M = ws + 16384; m = 64;  deg = 3; strip = b - 8; }
  else if (b < 14) { Wq = Wq2; Wk = Wk2; Wd = Wd2; M = ws + 20480; m = 32;  deg = 5; strip = b - 12; }
  else return;
  int r0 = strip * 16;
  if (r0 >= m) return;
  float scale = 1.0f / ((float)m * (float)m * sqrtf(1440.0f * (float)deg));
  for (int idx = threadIdx.x; idx < 16 * m; idx += 256) {
    int r = idx / m, c = idx % m;
    float s = 0.f;
    for (int a = 0; a < m; ++a) s += Wq[(r0 + r) * m + a] * Wd[a * m + c];
    T[r * m + c] = s;
  }
  __syncthreads();
  for (int idx = threadIdx.x; idx < 16 * m; idx += 256) {
    int r = idx / m, j = idx % m;
    float s = 0.f;
    for (int c = 0; c < m; ++c) s += T[r * m + c] * Wk[j * m + c];
    M[(r0 + r) * m + j] = s * scale;
  }
}

// ---------------------------------------------------------------------------
// K0b: pack B = [M_b | Wv_b/sqrt(m)] (bf16) in per-MFMA-fragment layout.
// Fragment = 1 KB: elem (l,j) = B[k = kt*32+(l>>4)*8+j][c = ct*16+(l&15)].
// B0: 64 frags ((ct*4)|kt, ct 0..15: cols 0..127 = M0, 128..255 = Wv0*sm)
// B1: 16 frags ((ct*2)|kt)   B2: 4 frags (ct)
// ---------------------------------------------------------------------------
__global__ __launch_bounds__(256) void pack_B(
    const float* __restrict__ Mtmp,
    const float* __restrict__ Wv0, const float* __restrict__ Wv1, const float* __restrict__ Wv2,
    unsigned short* __restrict__ Bp) {
  int idx = blockIdx.x * 256 + threadIdx.x;
  if (idx >= 43008) return;
  float val;
  if (idx < 32768) {
    int fragi = idx >> 9, rem = idx & 511;
    int l = rem >> 3, j = rem & 7;
    int ct = fragi >> 2, kt = fragi & 3;
    int k = kt * 32 + (l >> 4) * 8 + j;
    int c = ct * 16 + (l & 15);
    val = (c < 128) ? Mtmp[k * 128 + c] : Wv0[k * 128 + (c - 128)] * 0.08838834764831845f;
  } else if (idx < 40960) {
    int i1 = idx - 32768;
    int fragi = i1 >> 9, rem = i1 & 511;
    int l = rem >> 3, j = rem & 7;
    int ct = fragi >> 1, kt = fragi & 1;
    int k = kt * 32 + (l >> 4) * 8 + j;
    int c = ct * 16 + (l & 15);
    val = (c < 64) ? Mtmp[16384 + k * 64 + c] : Wv1[k * 64 + (c - 64)] * 0.125f;
  } else {
    int i2 = idx - 40960;
    int ct = i2 >> 9, rem = i2 & 511;
    int l = rem >> 3, j = rem & 7;
    int k = (l >> 4) * 8 + j;
    int c = ct * 16 + (l & 15);
    val = (c < 32) ? Mtmp[20480 + k * 32 + c] : Wv2[k * 32 + (c - 32)] * 0.17677669529663687f;
  }
  Bp[idx] = f2bf(val);
}

// ---------------------------------------------------------------------------
// Fused MFMA kernel. Block = 4 waves; each wave streams its own 16-node tiles
// through a wave-private LDS buffer (7680 bf16 = 30 col-blocks of 16x16,
// subtiled [cb][sub(4)][r(4)][pc(16)]). No __syncthreads anywhere.
// Permuted col space: p = c (c<128); p = 128+d*64+km (irrep1); 320+d*32+km.
// ---------------------------------------------------------------------------
__global__ __launch_bounds__(256) void fused_mfma_kernel(
    const float* __restrict__ f, const unsigned short* __restrict__ Bpack,
    const int* __restrict__ batch,
    float* __restrict__ outnum, float* __restrict__ norm,
    int N, int npw) {
  __shared__ __align__(16) unsigned short xs_all[4 * 7680];
  int t = threadIdx.x;
  int lane = t & 63;
  unsigned short* xs = xs_all + (t >> 6) * 7680;
  const char* xsb = (const char*)xs;

  int wid = blockIdx.x * 4 + (t >> 6);
  int wstart = wid * npw;
  if (wstart >= N) return;
  int wend = min(N, wstart + npw);

  const bf16x8* B0f = (const bf16x8*)Bpack;
  const bf16x8* B1f = (const bf16x8*)(Bpack + 32768);
  const bf16x8* B2f = (const bf16x8*)(Bpack + 40960);

  int q = lane >> 4, lm = lane & 15;
  int abase = (lm >> 2) * 128 + (lm & 3) * 32 + (q & 1) * 16;  // A-frag byte offset in cb-block
  int qh = q >> 1;

  float r0[8], r1[3][4], r2[5][2];
#pragma unroll
  for (int i = 0; i < 8; ++i) r0[i] = 0.f;
#pragma unroll
  for (int d = 0; d < 3; ++d)
#pragma unroll
    for (int i = 0; i < 4; ++i) r1[d][i] = 0.f;
#pragma unroll
  for (int d = 0; d < 5; ++d)
#pragma unroll
    for (int i = 0; i < 2; ++i) r2[d][i] = 0.f;
  float naccw = 0.f;
  int cur_g = -1;

  // flush current graph's accumulators (atomics; rare: graph boundaries only)
  auto flushf = [&](int g) {
    float* og = outnum + (size_t)g * 480;
#pragma unroll
    for (int ct = 0; ct < 8; ++ct) { atomicAdd(og + ct * 16 + lm, r0[ct]); r0[ct] = 0.f; }
#pragma unroll
    for (int d = 0; d < 3; ++d)
#pragma unroll
      for (int ct = 0; ct < 4; ++ct) {
        atomicAdd(og + 128 + 3 * (ct * 16 + lm) + d, r1[d][ct]); r1[d][ct] = 0.f;
      }
#pragma unroll
    for (int d = 0; d < 5; ++d)
#pragma unroll
      for (int ct = 0; ct < 2; ++ct) {
        atomicAdd(og + 320 + 5 * (ct * 16 + lm) + d, r2[d][ct]); r2[d][ct] = 0.f;
      }
    if (lm == 0) { atomicAdd(norm + g, naccw); naccw = 0.f; }
  };

  // weighted v-pass: v = x.[Wv] via MFMA, fold with (possibly masked) weights
  auto vpass = [&](float vw0, float vw1, float vw2, float vw3) {
    if (lm == 0) naccw += vw0 + vw1 + vw2 + vw3;
    {
      bf16x8 a0 = *(const bf16x8*)(xsb + (0 + qh) * 512 + abase);
      bf16x8 a1 = *(const bf16x8*)(xsb + (2 + qh) * 512 + abase);
      bf16x8 a2 = *(const bf16x8*)(xsb + (4 + qh) * 512 + abase);
      bf16x8 a3 = *(const bf16x8*)(xsb + (6 + qh) * 512 + abase);
#pragma unroll
      for (int ct = 0; ct < 8; ++ct) {
        f32x4 v = {0.f, 0.f, 0.f, 0.f};
        v = MFMA16(a0, B0f[((ct + 8) * 4 + 0) * 64 + lane], v);
        v = MFMA16(a1, B0f[((ct + 8) * 4 + 1) * 64 + lane], v);
        v = MFMA16(a2, B0f[((ct + 8) * 4 + 2) * 64 + lane], v);
        v = MFMA16(a3, B0f[((ct + 8) * 4 + 3) * 64 + lane], v);
        r0[ct] += vw0 * v[0] + vw1 * v[1] + vw2 * v[2] + vw3 * v[3];
      }
    }
#pragma unroll
    for (int d = 0; d < 3; ++d) {
      bf16x8 a0 = *(const bf16x8*)(xsb + (8 + d * 4 + 0 + qh) * 512 + abase);
      bf16x8 a1 = *(const bf16x8*)(xsb + (8 + d * 4 + 2 + qh) * 512 + abase);
#pragma unroll
      for (int ct = 0; ct < 4; ++ct) {
        f32x4 v = {0.f, 0.f, 0.f, 0.f};
        v = MFMA16(a0, B1f[((ct + 4) * 2 + 0) * 64 + lane], v);
        v = MFMA16(a1, B1f[((ct + 4) * 2 + 1) * 64 + lane], v);
        r1[d][ct] += vw0 * v[0] + vw1 * v[1] + vw2 * v[2] + vw3 * v[3];
      }
    }
#pragma unroll
    for (int d = 0; d < 5; ++d) {
      bf16x8 a0 = *(const bf16x8*)(xsb + (20 + d * 2 + qh) * 512 + abase);
#pragma unroll
      for (int ct = 0; ct < 2; ++ct) {
        f32x4 v = {0.f, 0.f, 0.f, 0.f};
        v = MFMA16(a0, B2f[(ct + 2) * 64 + lane], v);
        r2[d][ct] += vw0 * v[0] + vw1 * v[1] + vw2 * v[2] + vw3 * v[3];
      }
    }
  };

  for (int nt = wstart; nt < wend; nt += 16) {
    int valid = min(16, N - nt);

    // ---- stage 16x480 fp32 -> permuted subtiled bf16 LDS (wave-private) ----
    const float* fsrc = f + (size_t)nt * 480;
    for (int it = 0; it < 30; ++it) {
      int flat = it * 64 + lane;          // 0..1919
      int node = flat / 120;
      int e4 = flat - node * 120;
      float4 xv = make_float4(0.f, 0.f, 0.f, 0.f);
      if (node < valid) xv = reinterpret_cast<const float4*>(fsrc + node * 480)[e4];
      int bnr = (node >> 2) * 64 + (node & 3) * 16;
      int c = e4 * 4;
      if (c < 128) {
        ushort4 pk = make_ushort4(f2bf(xv.x), f2bf(xv.y), f2bf(xv.z), f2bf(xv.w));
        *reinterpret_cast<ushort4*>(&xs[(c >> 4) * 256 + bnr + (c & 15)]) = pk;
      } else if (c < 320) {
        float vv[4] = {xv.x, xv.y, xv.z, xv.w};
#pragma unroll
        for (int jj = 0; jj < 4; ++jj) {
          int qq = c + jj - 128;
          int km = qq / 3, d = qq - km * 3;
          xs[(8 + d * 4 + (km >> 4)) * 256 + bnr + (km & 15)] = f2bf(vv[jj]);
        }
      } else {
        float vv[4] = {xv.x, xv.y, xv.z, xv.w};
#pragma unroll
        for (int jj = 0; jj < 4; ++jj) {
          int qq = c + jj - 320;
          int km = qq / 5, d = qq - km * 5;
          xs[(20 + d * 2 + (km >> 4)) * 256 + bnr + (km & 15)] = f2bf(vv[jj]);
        }
      }
    }
    // same-wave LDS RAW: compiler inserts lgkmcnt waits; no barrier needed.

    // ---- u phase: logits via MFMA + C-frag dot with x ----
    float pl0 = 0.f, pl1 = 0.f, pl2 = 0.f, pl3 = 0.f;
    {
      bf16x8 a0 = *(const bf16x8*)(xsb + (0 + qh) * 512 + abase);
      bf16x8 a1 = *(const bf16x8*)(xsb + (2 + qh) * 512 + abase);
      bf16x8 a2 = *(const bf16x8*)(xsb + (4 + qh) * 512 + abase);
      bf16x8 a3 = *(const bf16x8*)(xsb + (6 + qh) * 512 + abase);
#pragma unroll
      for (int ct = 0; ct < 8; ++ct) {
        f32x4 u = {0.f, 0.f, 0.f, 0.f};
        u = MFMA16(a0, B0f[(ct * 4 + 0) * 64 + lane], u);
        u = MFMA16(a1, B0f[(ct * 4 + 1) * 64 + lane], u);
        u = MFMA16(a2, B0f[(ct * 4 + 2) * 64 + lane], u);
        u = MFMA16(a3, B0f[(ct * 4 + 3) * 64 + lane], u);
        int xo = ct * 256 + q * 64 + lm;
        pl0 += u[0] * bf2f(xs[xo]);
        pl1 += u[1] * bf2f(xs[xo + 16]);
        pl2 += u[2] * bf2f(xs[xo + 32]);
        pl3 += u[3] * bf2f(xs[xo + 48]);
      }
    }
#pragma unroll
    for (int d = 0; d < 3; ++d) {
      bf16x8 a0 = *(const bf16x8*)(xsb + (8 + d * 4 + 0 + qh) * 512 + abase);
      bf16x8 a1 = *(const bf16x8*)(xsb + (8 + d * 4 + 2 + qh) * 512 + abase);
#pragma unroll
      for (int ct = 0; ct < 4; ++ct) {
        f32x4 u = {0.f, 0.f, 0.f, 0.f};
        u = MFMA16(a0, B1f[(ct * 2 + 0) * 64 + lane], u);
        u = MFMA16(a1, B1f[(ct * 2 + 1) * 64 + lane], u);
        int xo = (8 + d * 4 + ct) * 256 + q * 64 + lm;
        pl0 += u[0] * bf2f(xs[xo]);
        pl1 += u[1] * bf2f(xs[xo + 16]);
        pl2 += u[2] * bf2f(xs[xo + 32]);
        pl3 += u[3] * bf2f(xs[xo + 48]);
      }
    }
#pragma unroll
    for (int d = 0; d < 5; ++d) {
      bf16x8 a0 = *(const bf16x8*)(xsb + (20 + d * 2 + qh) * 512 + abase);
#pragma unroll
      for (int ct = 0; ct < 2; ++ct) {
        f32x4 u = {0.f, 0.f, 0.f, 0.f};
        u = MFMA16(a0, B2f[ct * 64 + lane], u);
        int xo = (20 + d * 2 + ct) * 256 + q * 64 + lm;
        pl0 += u[0] * bf2f(xs[xo]);
        pl1 += u[1] * bf2f(xs[xo + 16]);
        pl2 += u[2] * bf2f(xs[xo + 32]);
        pl3 += u[3] * bf2f(xs[xo + 48]);
      }
    }
#pragma unroll
    for (int off = 1; off < 16; off <<= 1) {
      pl0 += __shfl_xor(pl0, off);
      pl1 += __shfl_xor(pl1, off);
      pl2 += __shfl_xor(pl2, off);
      pl3 += __shfl_xor(pl3, off);
    }
    float w0 = (q * 4 + 0 < valid) ? __expf(pl0) : 0.f;
    float w1 = (q * 4 + 1 < valid) ? __expf(pl1) : 0.f;
    float w2 = (q * 4 + 2 < valid) ? __expf(pl2) : 0.f;
    float w3 = (q * 4 + 3 < valid) ? __expf(pl3) : 0.f;

    // ---- wave-scalar segmentation over sorted batch ----
    int gl = batch[nt + (lm < valid ? lm : valid - 1)];
    int gp = __shfl(gl, (lane == 0) ? 0 : lane - 1);
    unsigned long long bm = __ballot(lm > 0 && lm < valid && gl != gp);
    unsigned segm = (unsigned)bm & 0xFFFEu;
    int g0 = __shfl(gl, 0);

    if (segm == 0) {
      if (g0 != cur_g) { if (cur_g >= 0) flushf(cur_g); cur_g = g0; }
      vpass(w0, w1, w2, w3);
    } else {
      int a = 0;
      while (a < valid) {
        unsigned hi = segm & ~((1u << (a + 1)) - 1u);
        int b = hi ? (int)__builtin_ctz(hi) : valid;
        int gs = __shfl(gl, a);
        if (gs != cur_g) { if (cur_g >= 0) flushf(cur_g); cur_g = gs; }
        int nq = q * 4;
        float m0 = (nq + 0 >= a && nq + 0 < b) ? w0 : 0.f;
        float m1 = (nq + 1 >= a && nq + 1 < b) ? w1 : 0.f;
        float m2 = (nq + 2 >= a && nq + 2 < b) ? w2 : 0.f;
        float m3 = (nq + 3 >= a && nq + 3 < b) ? w3 : 0.f;
        vpass(m0, m1, m2, m3);
        a = b;
      }
    }
  }
  if (cur_g >= 0) flushf(cur_g);
}

// ---------------------------------------------------------------------------
// finalize: out = num / max(norm, 1e-8)
// ---------------------------------------------------------------------------
__global__ __launch_bounds__(256) void finalize_kernel(
    float* __restrict__ out, const float* __restrict__ norm, int total) {
  int idx = blockIdx.x * blockDim.x + threadIdx.x;
  if (idx < total) {
    int g = idx / 480;
    out[idx] = out[idx] / fmaxf(norm[g], 1e-8f);
  }
}

extern "C" void kernel_launch(void* const* d_in, const int* in_sizes, int n_in,
                              void* d_out, int out_size, void* d_ws, size_t ws_size,
                              hipStream_t stream) {
  const float* f   = (const float*)d_in[0];
  const float* Wv0 = (const float*)d_in[7];
  const float* Wv1 = (const float*)d_in[8];
  const float* Wv2 = (const float*)d_in[9];
  const int* batch = (const int*)d_in[13];

  int N = in_sizes[0] / D_TOT;
  int G = out_size / D_TOT;

  // ws byte layout: [0,86016) Mtmp fp32; [86016,172032) Bpack bf16; [172032,..) norm
  float* Mtmp = (float*)d_ws;
  unsigned short* Bpack = (unsigned short*)((char*)d_ws + 86016);
  float* norm = (float*)((char*)d_ws + 172032);
  float* out  = (float*)d_out;

  hipMemsetAsync(d_out, 0, (size_t)out_size * sizeof(float), stream);
  hipMemsetAsync(norm, 0, (size_t)G * sizeof(float), stream);

  precompute_M<<<14, 256, 0, stream>>>(
      (const float*)d_in[1], (const float*)d_in[2], (const float*)d_in[3],
      (const float*)d_in[4], (const float*)d_in[5], (const float*)d_in[6],
      (const float*)d_in[10], (const float*)d_in[11], (const float*)d_in[12], Mtmp);

  pack_B<<<(43008 + 255) / 256, 256, 0, stream>>>(Mtmp, Wv0, Wv1, Wv2, Bpack);

  // ~2048 waves total (2 blocks/CU x 256 CU x 4 waves), 16-aligned node range/wave
  int npw = ((N + 2047) / 2048 + 15) / 16 * 16;
  if (npw < 16) npw = 16;
  int nwaves = (N + npw - 1) / npw;
  int nblocks = (nwaves + 3) / 4;

  fused_mfma_kernel<<<nblocks, 256, 0, stream>>>(f, Bpack, batch, out, norm, N, npw);

  finalize_kernel<<<(G * D_TOT + 255) / 256, 256, 0, stream>>>(out, norm, G * D_TOT);
}

// Round 4
// 496.680 us; speedup vs baseline: 8.0655x; 1.6526x over previous
//
#include <hip/hip_runtime.h>
#include <math.h>

#define D_TOT 480

typedef short bf16x8 __attribute__((ext_vector_type(8)));
typedef float f32x4 __attribute__((ext_vector_type(4)));

#define MFMA16(a, b, c) __builtin_amdgcn_mfma_f32_16x16x32_bf16((a), (b), (c), 0, 0, 0)

static __device__ __forceinline__ unsigned short f2bf(float x) {
  unsigned u = __float_as_uint(x);
  u += 0x7FFFu + ((u >> 16) & 1u);   // RNE (inputs finite)
  return (unsigned short)(u >> 16);
}
static __device__ __forceinline__ float bf2f(unsigned short v) {
  return __uint_as_float(((unsigned)v) << 16);
}

// ---------------------------------------------------------------------------
// K0: Mtmp_b = (Wq_b . Wd_b . Wk_b^T) * scale_b (fp32), scale folds all norms:
//   scale_b = 1 / (m^2 * sqrt(1440*d)).
// ws fp32 layout: M0 [0,16384), M1 [16384,20480), M2 [20480,21504)
// ---------------------------------------------------------------------------
__global__ __launch_bounds__(256) void precompute_M(
    const float* __restrict__ Wq0, const float* __restrict__ Wq1, const float* __restrict__ Wq2,
    const float* __restrict__ Wk0, const float* __restrict__ Wk1, const float* __restrict__ Wk2,
    const float* __restrict__ Wd0, const float* __restrict__ Wd1, const float* __restrict__ Wd2,
    float* __restrict__ ws) {
  __shared__ float T[16 * 128];
  int b = blockIdx.x;
  const float *Wq, *Wk, *Wd;
  float* M;
  int m, deg, strip;
  if (b < 8)       { Wq = Wq0; Wk = Wk0; Wd = Wd0; M = ws;         m = 128; deg = 1; strip = b; }
  else if (b < 12) { Wq = Wq1; Wk = Wk1; Wd = Wd1; M = ws + 16384; m = 64;  deg = 3; strip = b - 8; }
  else if (b < 14) { Wq = Wq2; Wk = Wk2; Wd = Wd2; M = ws + 20480; m = 32;  deg = 5; strip = b - 12; }
  else return;
  int r0 = strip * 16;
  if (r0 >= m) return;
  float scale = 1.0f / ((float)m * (float)m * sqrtf(1440.0f * (float)deg));
  for (int idx = threadIdx.x; idx < 16 * m; idx += 256) {
    int r = idx / m, c = idx % m;
    float s = 0.f;
    for (int a = 0; a < m; ++a) s += Wq[(r0 + r) * m + a] * Wd[a * m + c];
    T[r * m + c] = s;
  }
  __syncthreads();
  for (int idx = threadIdx.x; idx < 16 * m; idx += 256) {
    int r = idx / m, j = idx % m;
    float s = 0.f;
    for (int c = 0; c < m; ++c) s += T[r * m + c] * Wk[j * m + c];
    M[(r0 + r) * m + j] = s * scale;
  }
}

// ---------------------------------------------------------------------------
// K0b: pack B = [M_b | Wv_b/sqrt(m)] (bf16) in per-MFMA-fragment layout.
// Fragment = 1 KB: elem (l,j) = B[k = kt*32+(l>>4)*8+j][c = ct*16+(l&15)].
// B0: 64 frags ((ct*4)|kt, ct 0..15: cols 0..127 = M0, 128..255 = Wv0*sm)
// B1: 16 frags ((ct*2)|kt)   B2: 4 frags (ct)
// ---------------------------------------------------------------------------
__global__ __launch_bounds__(256) void pack_B(
    const float* __restrict__ Mtmp,
    const float* __restrict__ Wv0, const float* __restrict__ Wv1, const float* __restrict__ Wv2,
    unsigned short* __restrict__ Bp) {
  int idx = blockIdx.x * 256 + threadIdx.x;
  if (idx >= 43008) return;
  float val;
  if (idx < 32768) {
    int fragi = idx >> 9, rem = idx & 511;
    int l = rem >> 3, j = rem & 7;
    int ct = fragi >> 2, kt = fragi & 3;
    int k = kt * 32 + (l >> 4) * 8 + j;
    int c = ct * 16 + (l & 15);
    val = (c < 128) ? Mtmp[k * 128 + c] : Wv0[k * 128 + (c - 128)] * 0.08838834764831845f;
  } else if (idx < 40960) {
    int i1 = idx - 32768;
    int fragi = i1 >> 9, rem = i1 & 511;
    int l = rem >> 3, j = rem & 7;
    int ct = fragi >> 1, kt = fragi & 1;
    int k = kt * 32 + (l >> 4) * 8 + j;
    int c = ct * 16 + (l & 15);
    val = (c < 64) ? Mtmp[16384 + k * 64 + c] : Wv1[k * 64 + (c - 64)] * 0.125f;
  } else {
    int i2 = idx - 40960;
    int ct = i2 >> 9, rem = i2 & 511;
    int l = rem >> 3, j = rem & 7;
    int k = (l >> 4) * 8 + j;
    int c = ct * 16 + (l & 15);
    val = (c < 32) ? Mtmp[20480 + k * 32 + c] : Wv2[k * 32 + (c - 32)] * 0.17677669529663687f;
  }
  Bp[idx] = f2bf(val);
}

// ---------------------------------------------------------------------------
// Fused MFMA kernel, one 16-node tile per wave (12500 waves at N=200000).
// LDS: natural layout, row = node (1024 B), XOR swizzle byte^=(node&7)<<4.
// Staging: 30x vectorized float4 -> 4xbf16 -> ds_write_b64 (no scatter).
// A-frags gathered ONCE into registers: irrep0 via ds_read_b128,
// irrep1/2 via 88 scalar u16 gathers; reused for u-phase, v-pass, segments.
// ---------------------------------------------------------------------------
__global__ __launch_bounds__(256, 2) void fused_mfma_kernel(
    const float* __restrict__ f, const unsigned short* __restrict__ Bpack,
    const int* __restrict__ batch,
    float* __restrict__ outnum, float* __restrict__ norm, int N) {
  __shared__ __align__(16) unsigned short xs_all[4 * 8192];
  int t = threadIdx.x;
  int lane = t & 63;
  char* xsb = (char*)(xs_all + (t >> 6) * 8192);

  int wid = blockIdx.x * 4 + (t >> 6);
  int nt = wid * 16;
  if (nt >= N) return;
  int valid = min(16, N - nt);

  int q = lane >> 4, lm = lane & 15;
  unsigned swzlm = (unsigned)((lm & 7) << 4);

  const bf16x8* B0f = (const bf16x8*)Bpack;
  const bf16x8* B1f = (const bf16x8*)(Bpack + 32768);
  const bf16x8* B2f = (const bf16x8*)(Bpack + 40960);

  // ---- stage: 16 nodes x 480 fp32 -> natural bf16 rows (swizzled) ----
  {
    int ns = lane >> 2, e0 = lane & 3;
    const float* frow = f + (size_t)(nt + ns) * 480;
    char* wrow = xsb + ns * 1024;
    unsigned swzw = (unsigned)((ns & 7) << 4);
    bool okn = ns < valid;
#pragma unroll
    for (int i = 0; i < 30; ++i) {
      int e4 = e0 + i * 4;
      float4 xv = make_float4(0.f, 0.f, 0.f, 0.f);
      if (okn) xv = reinterpret_cast<const float4*>(frow)[e4];
      unsigned p0 = (unsigned)f2bf(xv.x) | ((unsigned)f2bf(xv.y) << 16);
      unsigned p1 = (unsigned)f2bf(xv.z) | ((unsigned)f2bf(xv.w) << 16);
      *reinterpret_cast<uint2*>(wrow + (((unsigned)(e4 * 8)) ^ swzw)) = make_uint2(p0, p1);
    }
  }
  int gl = batch[nt + (lm < valid ? lm : valid - 1)];

  // ---- gather A-frags into registers (row = lm, k-chunk = q) ----
  const char* arow = xsb + lm * 1024;
  bf16x8 a0[4];
#pragma unroll
  for (int ks = 0; ks < 4; ++ks)
    a0[ks] = *reinterpret_cast<const bf16x8*>(arow + (((unsigned)(ks * 64 + q * 16)) ^ swzlm));
  bf16x8 a1[3][2];
#pragma unroll
  for (int d = 0; d < 3; ++d)
#pragma unroll
    for (int h = 0; h < 2; ++h) {
      bf16x8 v;
#pragma unroll
      for (int j = 0; j < 8; ++j) {
        int km = h * 32 + q * 8 + j;
        unsigned off = ((unsigned)(2 * (128 + 3 * km + d))) ^ swzlm;
        v[j] = (short)*reinterpret_cast<const unsigned short*>(arow + off);
      }
      a1[d][h] = v;
    }
  bf16x8 a2[5];
#pragma unroll
  for (int d = 0; d < 5; ++d) {
    bf16x8 v;
#pragma unroll
    for (int j = 0; j < 8; ++j) {
      int km = q * 8 + j;
      unsigned off = ((unsigned)(2 * (320 + 5 * km + d))) ^ swzlm;
      v[j] = (short)*reinterpret_cast<const unsigned short*>(arow + off);
    }
    a2[d] = v;
  }

  // x read in C-frag order for the logit dot: node = q*4+j, natural col c
  auto ldx = [&](int node, int c) -> float {
    unsigned off = ((unsigned)(2 * c)) ^ ((unsigned)((node & 7) << 4));
    return bf2f(*reinterpret_cast<const unsigned short*>(xsb + node * 1024 + off));
  };

  // ---- u-phase: logits ----
  float pl0 = 0.f, pl1 = 0.f, pl2 = 0.f, pl3 = 0.f;
#pragma unroll
  for (int ct = 0; ct < 8; ++ct) {
    f32x4 u = {0.f, 0.f, 0.f, 0.f};
    u = MFMA16(a0[0], B0f[(ct * 4 + 0) * 64 + lane], u);
    u = MFMA16(a0[1], B0f[(ct * 4 + 1) * 64 + lane], u);
    u = MFMA16(a0[2], B0f[(ct * 4 + 2) * 64 + lane], u);
    u = MFMA16(a0[3], B0f[(ct * 4 + 3) * 64 + lane], u);
    int c = ct * 16 + lm;
    pl0 += u[0] * ldx(q * 4 + 0, c);
    pl1 += u[1] * ldx(q * 4 + 1, c);
    pl2 += u[2] * ldx(q * 4 + 2, c);
    pl3 += u[3] * ldx(q * 4 + 3, c);
  }
#pragma unroll
  for (int d = 0; d < 3; ++d)
#pragma unroll
    for (int ct = 0; ct < 4; ++ct) {
      f32x4 u = {0.f, 0.f, 0.f, 0.f};
      u = MFMA16(a1[d][0], B1f[(ct * 2 + 0) * 64 + lane], u);
      u = MFMA16(a1[d][1], B1f[(ct * 2 + 1) * 64 + lane], u);
      int c = 128 + 3 * (ct * 16 + lm) + d;
      pl0 += u[0] * ldx(q * 4 + 0, c);
      pl1 += u[1] * ldx(q * 4 + 1, c);
      pl2 += u[2] * ldx(q * 4 + 2, c);
      pl3 += u[3] * ldx(q * 4 + 3, c);
    }
#pragma unroll
  for (int d = 0; d < 5; ++d)
#pragma unroll
    for (int ct = 0; ct < 2; ++ct) {
      f32x4 u = {0.f, 0.f, 0.f, 0.f};
      u = MFMA16(a2[d], B2f[ct * 64 + lane], u);
      int c = 320 + 5 * (ct * 16 + lm) + d;
      pl0 += u[0] * ldx(q * 4 + 0, c);
      pl1 += u[1] * ldx(q * 4 + 1, c);
      pl2 += u[2] * ldx(q * 4 + 2, c);
      pl3 += u[3] * ldx(q * 4 + 3, c);
    }
#pragma unroll
  for (int off = 1; off < 16; off <<= 1) {
    pl0 += __shfl_xor(pl0, off);
    pl1 += __shfl_xor(pl1, off);
    pl2 += __shfl_xor(pl2, off);
    pl3 += __shfl_xor(pl3, off);
  }
  float w0 = (q * 4 + 0 < valid) ? __expf(pl0) : 0.f;
  float w1 = (q * 4 + 1 < valid) ? __expf(pl1) : 0.f;
  float w2 = (q * 4 + 2 < valid) ? __expf(pl2) : 0.f;
  float w3 = (q * 4 + 3 < valid) ? __expf(pl3) : 0.f;

  // ---- v accumulators ----
  float r0[8], r1[3][4], r2[5][2], naccw = 0.f;
#pragma unroll
  for (int i = 0; i < 8; ++i) r0[i] = 0.f;
#pragma unroll
  for (int d = 0; d < 3; ++d)
#pragma unroll
    for (int i = 0; i < 4; ++i) r1[d][i] = 0.f;
#pragma unroll
  for (int d = 0; d < 5; ++d)
#pragma unroll
    for (int i = 0; i < 2; ++i) r2[d][i] = 0.f;

  auto vpass = [&](float vw0, float vw1, float vw2, float vw3) {
    if (lm == 0) naccw += vw0 + vw1 + vw2 + vw3;
#pragma unroll
    for (int ct = 0; ct < 8; ++ct) {
      f32x4 v = {0.f, 0.f, 0.f, 0.f};
      v = MFMA16(a0[0], B0f[((ct + 8) * 4 + 0) * 64 + lane], v);
      v = MFMA16(a0[1], B0f[((ct + 8) * 4 + 1) * 64 + lane], v);
      v = MFMA16(a0[2], B0f[((ct + 8) * 4 + 2) * 64 + lane], v);
      v = MFMA16(a0[3], B0f[((ct + 8) * 4 + 3) * 64 + lane], v);
      r0[ct] += vw0 * v[0] + vw1 * v[1] + vw2 * v[2] + vw3 * v[3];
    }
#pragma unroll
    for (int d = 0; d < 3; ++d)
#pragma unroll
      for (int ct = 0; ct < 4; ++ct) {
        f32x4 v = {0.f, 0.f, 0.f, 0.f};
        v = MFMA16(a1[d][0], B1f[((ct + 4) * 2 + 0) * 64 + lane], v);
        v = MFMA16(a1[d][1], B1f[((ct + 4) * 2 + 1) * 64 + lane], v);
        r1[d][ct] += vw0 * v[0] + vw1 * v[1] + vw2 * v[2] + vw3 * v[3];
      }
#pragma unroll
    for (int d = 0; d < 5; ++d)
#pragma unroll
      for (int ct = 0; ct < 2; ++ct) {
        f32x4 v = {0.f, 0.f, 0.f, 0.f};
        v = MFMA16(a2[d], B2f[(ct + 2) * 64 + lane], v);
        r2[d][ct] += vw0 * v[0] + vw1 * v[1] + vw2 * v[2] + vw3 * v[3];
      }
  };

  auto wavered = [&](float s) -> float {
    s += __shfl_xor(s, 16);
    s += __shfl_xor(s, 32);
    return s;
  };
  auto flushf = [&](int g) {
    float* og = outnum + (size_t)g * 480;
#pragma unroll
    for (int ct = 0; ct < 8; ++ct) {
      float s = wavered(r0[ct]);
      if (lane < 16) atomicAdd(og + ct * 16 + lane, s);
      r0[ct] = 0.f;
    }
#pragma unroll
    for (int d = 0; d < 3; ++d)
#pragma unroll
      for (int ct = 0; ct < 4; ++ct) {
        float s = wavered(r1[d][ct]);
        if (lane < 16) atomicAdd(og + 128 + 3 * (ct * 16 + lane) + d, s);
        r1[d][ct] = 0.f;
      }
#pragma unroll
    for (int d = 0; d < 5; ++d)
#pragma unroll
      for (int ct = 0; ct < 2; ++ct) {
        float s = wavered(r2[d][ct]);
        if (lane < 16) atomicAdd(og + 320 + 5 * (ct * 16 + lane) + d, s);
        r2[d][ct] = 0.f;
      }
    float sw = wavered(naccw);
    if (lane == 0) atomicAdd(norm + g, sw);
    naccw = 0.f;
  };

  // ---- segmented (sorted-batch) accumulation over this tile ----
  int gp = __shfl(gl, (lane == 0) ? 0 : lane - 1);
  unsigned long long bm = __ballot(lm > 0 && lm < valid && gl != gp);
  unsigned segm = (unsigned)bm & 0xFFFEu;

  int cur_g = -1;
  int a = 0;
  while (a < valid) {
    unsigned hi = segm & ~((1u << (a + 1)) - 1u);
    int b = hi ? (int)__builtin_ctz(hi) : valid;
    int gs = __shfl(gl, a);
    if (cur_g >= 0) flushf(cur_g);
    cur_g = gs;
    int nq = q * 4;
    float m0 = (nq + 0 >= a && nq + 0 < b) ? w0 : 0.f;
    float m1 = (nq + 1 >= a && nq + 1 < b) ? w1 : 0.f;
    float m2 = (nq + 2 >= a && nq + 2 < b) ? w2 : 0.f;
    float m3 = (nq + 3 >= a && nq + 3 < b) ? w3 : 0.f;
    vpass(m0, m1, m2, m3);
    a = b;
  }
  if (cur_g >= 0) flushf(cur_g);
}

// ---------------------------------------------------------------------------
// finalize: out = num / max(norm, 1e-8)
// ---------------------------------------------------------------------------
__global__ __launch_bounds__(256) void finalize_kernel(
    float* __restrict__ out, const float* __restrict__ norm, int total) {
  int idx = blockIdx.x * blockDim.x + threadIdx.x;
  if (idx < total) {
    int g = idx / 480;
    out[idx] = out[idx] / fmaxf(norm[g], 1e-8f);
  }
}

extern "C" void kernel_launch(void* const* d_in, const int* in_sizes, int n_in,
                              void* d_out, int out_size, void* d_ws, size_t ws_size,
                              hipStream_t stream) {
  const float* f   = (const float*)d_in[0];
  const float* Wv0 = (const float*)d_in[7];
  const float* Wv1 = (const float*)d_in[8];
  const float* Wv2 = (const float*)d_in[9];
  const int* batch = (const int*)d_in[13];

  int N = in_sizes[0] / D_TOT;
  int G = out_size / D_TOT;

  // ws byte layout: [0,86016) Mtmp fp32; [86016,172032) Bpack bf16; [172032,..) norm
  float* Mtmp = (float*)d_ws;
  unsigned short* Bpack = (unsigned short*)((char*)d_ws + 86016);
  float* norm = (float*)((char*)d_ws + 172032);
  float* out  = (float*)d_out;

  hipMemsetAsync(d_out, 0, (size_t)out_size * sizeof(float), stream);
  hipMemsetAsync(norm, 0, (size_t)G * sizeof(float), stream);

  precompute_M<<<14, 256, 0, stream>>>(
      (const float*)d_in[1], (const float*)d_in[2], (const float*)d_in[3],
      (const float*)d_in[4], (const float*)d_in[5], (const float*)d_in[6],
      (const float*)d_in[10], (const float*)d_in[11], (const float*)d_in[12], Mtmp);

  pack_B<<<(43008 + 255) / 256, 256, 0, stream>>>(Mtmp, Wv0, Wv1, Wv2, Bpack);

  int nwaves = (N + 15) / 16;
  int nblocks = (nwaves + 3) / 4;
  fused_mfma_kernel<<<nblocks, 256, 0, stream>>>(f, Bpack, batch, out, norm, N);

  finalize_kernel<<<(G * D_TOT + 255) / 256, 256, 0, stream>>>(out, norm, G * D_TOT);
}